// Round 10
// baseline (90.207 us; speedup 1.0000x reference)
//
#include <hip/hip_runtime.h>
#include <stdint.h>

#define T_STEPS 2048
#define NCHUNK  86            // 85 full 24-step chunks + one 8-step tail
#define LARGEF  1.0e9f
typedef unsigned long long u64;
typedef unsigned uint2v __attribute__((ext_vector_type(2)));

__device__ __forceinline__ int par6(int x) { return __builtin_popcount((unsigned)x) & 1; }

// dual-basis functionals C; exchange masks m={1,2,7,15,16,32} (verified r2-r9)
constexpr int CARR[6] = {5, 6, 12, 8, 16, 32};

template<int CTRL>
__device__ __forceinline__ float xdpp(float x) {
  return __int_as_float(__builtin_amdgcn_update_dpp(0, __float_as_int(x), CTRL, 0xF, 0xF, true));
}
template<int CTRL>
__device__ __forceinline__ unsigned xdpp_u(unsigned x) {
  return (unsigned)__builtin_amdgcn_update_dpp(0, (int)x, CTRL, 0xF, 0xF, true);
}
__device__ __forceinline__ unsigned selmask_u(unsigned a_false, unsigned b_true, u64 m) {
  unsigned out;
  asm("v_cndmask_b32 %0, %1, %2, %3" : "=v"(out) : "v"(a_false), "v"(b_true), "s"(m));
  return out;
}
__device__ __forceinline__ unsigned exch16_u(unsigned x, u64 mrx) {
#if __has_builtin(__builtin_amdgcn_permlane16_swap)
  uint2v r = __builtin_amdgcn_permlane16_swap(x, x, false, false);
  return selmask_u(r.y, r.x, mrx);
#else
  (void)mrx;
  return (unsigned)__builtin_amdgcn_ds_swizzle((int)x, 0x401F);
#endif
}
__device__ __forceinline__ unsigned exch32_u(unsigned x, u64 mrx) {
#if __has_builtin(__builtin_amdgcn_permlane32_swap)
  uint2v r = __builtin_amdgcn_permlane32_swap(x, x, false, false);
  return selmask_u(r.y, r.x, mrx);
#else
  (void)mrx;
  return (unsigned)__shfl_xor((int)x, 32, 64);
#endif
}
template<int PH>
__device__ __forceinline__ float exchf(float x, const u64 (&mrx)[2]) {
  if constexpr (PH == 0) return xdpp<0xB1>(x);        // xor 1
  else if constexpr (PH == 1) return xdpp<0x4E>(x);   // xor 2
  else if constexpr (PH == 2) return xdpp<0x141>(x);  // xor 7
  else if constexpr (PH == 3) return xdpp<0x140>(x);  // xor 15
  else if constexpr (PH == 4) return __uint_as_float(exch16_u(__float_as_uint(x), mrx[0]));
  else return __uint_as_float(exch32_u(__float_as_uint(x), mrx[1]));
}
template<int PH>
__device__ __forceinline__ unsigned exchu(unsigned x, const u64 (&mrx)[2]) {
  if constexpr (PH == 0) return xdpp_u<0xB1>(x);
  else if constexpr (PH == 1) return xdpp_u<0x4E>(x);
  else if constexpr (PH == 2) return xdpp_u<0x141>(x);
  else if constexpr (PH == 3) return xdpp_u<0x140>(x);
  else if constexpr (PH == 4) return exch16_u(x, mrx[0]);
  else return exch32_u(x, mrx[1]);
}

template<int K>
__device__ __forceinline__ float getbm(const float4 (&bk)[6]) {
  constexpr int j = K >> 2;
  if constexpr ((K & 3) == 0) return bk[j].x;
  else if constexpr ((K & 3) == 1) return bk[j].y;
  else if constexpr ((K & 3) == 2) return bk[j].z;
  else return bk[j].w;
}

// ---- wave0: N ACS steps; dw = 2*dw + d each step (d_K lands at bit N-1-K) ----
template<int N, int K>
__device__ __forceinline__ void acsr(float& cum, unsigned& dw, const float4 (&bk)[6],
                                     const unsigned (&sgn)[6], const u64 (&mrx)[2]) {
  if constexpr (K < N) {
    constexpr int ph = K % 6;
    const float bmk = getbm<K>(bk);
    const float ex = exchf<ph>(cum, mrx);
    const float cA = cum + bmk;     // own-pred candidate
    const float cB = ex - bmk;      // partner-pred candidate
    const float D = cA - cB;        // sign exact; zero iff true tie
    cum = fminf(cA, cB);
    unsigned tmp;
    asm("v_xor_b32 %0, %2, %3\n\t"
        "v_cmp_gt_f32 vcc, 0, %0\n\t"
        "v_addc_co_u32 %1, vcc, %1, %1, vcc"
        : "=&v"(tmp), "+v"(dw)
        : "v"(D), "v"(sgn[ph]) : "vcc");
    acsr<N, K + 1>(cum, dw, bk, sgn, mrx);
  }
}

// ---- wave1: reconstruct path/anc word from d-bits (tp = d XOR pd) ----
template<int N, int K>
__device__ __forceinline__ void wrec(unsigned& word, unsigned& dws, const unsigned (&pdu)[6],
                                     const u64 (&pdm)[6], const u64 (&mrx)[2]) {
  if constexpr (K < N) {
    constexpr int ph = K % 6;
    const unsigned exw = exchu<ph>(word, mrx);
    asm("v_cmp_gt_i32 vcc, 0, %1\n\t"
        "v_add_u32 %1, %1, %1\n\t"
        "s_xor_b64 vcc, vcc, %3\n\t"
        "v_cndmask_b32 %0, %0, %2, vcc"
        : "+v"(word), "+v"(dws)
        : "v"(exw), "s"(pdm[ph]) : "vcc");
    word |= pdu[ph] << (6 + K);
    wrec<N, K + 1>(word, dws, pdu, pdm, mrx);
  }
}

// ---- wave1: compute N branch metrics for chunk starting at ych, write to dst ----
template<int N>
__device__ __forceinline__ void bmw(const float* ych, float* dst,
                                    const float (&sae)[6], const float (&sbe)[6]) {
  const float4* y4 = (const float4*)ych;   // uniform LDS reads (broadcast)
  float4* d4 = (float4*)dst;
#pragma unroll
  for (int j = 0; j < N / 4; ++j) {
    const float4 qa = y4[2 * j];
    const float4 qb = y4[2 * j + 1];
    float4 r;
    r.x = fmaf(sae[(4 * j + 0) % 6], qa.x, sbe[(4 * j + 0) % 6] * qa.y);  // bit-exact vs ref
    r.y = fmaf(sae[(4 * j + 1) % 6], qa.z, sbe[(4 * j + 1) % 6] * qa.w);
    r.z = fmaf(sae[(4 * j + 2) % 6], qb.x, sbe[(4 * j + 2) % 6] * qb.y);
    r.w = fmaf(sae[(4 * j + 3) % 6], qb.z, sbe[(4 * j + 3) % 6] * qb.w);
    d4[j] = r;
  }
}

__global__ __launch_bounds__(128, 1) void viterbi_kernel(const float* __restrict__ in,
                                                         float* __restrict__ out) {
  __shared__ float y_lds[2 * T_STEPS];        // 16 KB input row
  __shared__ float bmld[3][64][24];           // 18 KB bm triple buffer
  __shared__ unsigned dwld[2][64];            // 0.5 KB d-bit handoff
  __shared__ unsigned tbf[NCHUNK][64];        // 21.5 KB path/anc words
  __shared__ int lam_sh;

  const int tid = threadIdx.x;
  const int lane = tid & 63;
  const int w = tid >> 6;
  const int b = blockIdx.x;

  // ---- stage y (both waves, coalesced float4) ----
  {
    const float4* g = (const float4*)(in + (size_t)b * (2 * T_STEPS));
    float4* l = (float4*)y_lds;
#pragma unroll
    for (int i = 0; i < 8; ++i) l[i * 128 + tid] = g[i * 128 + tid];
  }

  // ---- per-phase lane constants (both waves) ----
  float sae[6], sbe[6];
  unsigned pdu[6], sgn[6];
  u64 pdm[6], mrx[2];
#pragma unroll
  for (int ph = 0; ph < 6; ++ph) {
    const int pdv = par6(lane & CARR[ph]);
    int t = 0;
#pragma unroll
    for (int j = 0; j < 5; ++j) t |= par6(lane & CARR[(ph + 1 + j) % 6]) << j;
    t |= pdv << 5;
    const float sa = 1.0f - 2.0f * (float)par6(t & 45);   // poly 1011011
    const float sb = 1.0f - 2.0f * (float)par6(t & 60);   // poly 1111001
    sae[ph] = pdv ? -sa : sa;
    sbe[ph] = pdv ? -sb : sb;
    pdu[ph] = (unsigned)pdv;
    sgn[ph] = pdv ? 0u : 0x80000000u;
    pdm[ph] = __ballot(pdv != 0);
  }
  {
    const u64 ODD16 = 0xFFFF0000FFFF0000ull;
    const u64 HI32 = 0xFFFFFFFF00000000ull;
#if __has_builtin(__builtin_amdgcn_permlane16_swap)
    uint2v p16 = __builtin_amdgcn_permlane16_swap((unsigned)lane, (unsigned)lane, false, false);
    mrx[0] = (((unsigned)__builtin_amdgcn_readlane((int)p16.x, 0) == 16u)) ? ~ODD16 : ODD16;
#else
    mrx[0] = 0;
#endif
#if __has_builtin(__builtin_amdgcn_permlane32_swap)
    uint2v p32 = __builtin_amdgcn_permlane32_swap((unsigned)lane, (unsigned)lane, false, false);
    mrx[1] = (((unsigned)__builtin_amdgcn_readlane((int)p32.x, 0) == 32u)) ? ~HI32 : HI32;
#else
    mrx[1] = 0;
#endif
  }
  __syncthreads();

  // ---- prologue: wave1 fills bm[0], bm[1] ----
  if (w == 1) {
    bmw<24>(y_lds + 0, &bmld[0][lane][0], sae, sbe);
    bmw<24>(y_lds + 48, &bmld[1][lane][0], sae, sbe);
  }
  __syncthreads();

  float cum = (lane == 0) ? 0.0f : LARGEF;
  unsigned dw = 0;
  float4 bk0[6], bk1[6];
  if (w == 0) {   // preload bm[0] (buf0 -> bank0)
    const float4* p = (const float4*)&bmld[0][lane][0];
#pragma unroll
    for (int j = 0; j < 6; ++j) bk0[j] = p[j];
  }

  // ---- main loop: it = base+J, J=0..5 static (6 | base keeps %3,&1 static) ----
#define W0_BLOCK(J)                                                                     \
  {                                                                                     \
    const float4* p = (const float4*)&bmld[((J) + 1) % 3][lane][0];                     \
    if constexpr (((J) & 1) == 0) {                                                     \
      _Pragma("unroll") for (int j = 0; j < 6; ++j) bk1[j] = p[j];                      \
      acsr<24, 0>(cum, dw, bk0, sgn, mrx);                                              \
    } else {                                                                            \
      _Pragma("unroll") for (int j = 0; j < 6; ++j) bk0[j] = p[j];                      \
      acsr<24, 0>(cum, dw, bk1, sgn, mrx);                                              \
    }                                                                                   \
    dwld[(J) & 1][lane] = dw;                                                           \
    dw = 0;                                                                             \
  }
#define W1_BLOCK(J)                                                                     \
  {                                                                                     \
    const int c2 = base + (J) + 2;                                                      \
    if (c2 != 85) bmw<24>(y_lds + 48 * c2, &bmld[((J) + 2) % 3][lane][0], sae, sbe);    \
    else          bmw<8>(y_lds + 48 * c2, &bmld[((J) + 2) % 3][lane][0], sae, sbe);     \
    if (base + (J) >= 1) {                                                              \
      unsigned dws = dwld[((J) + 1) & 1][lane] << 8;                                    \
      unsigned word = (unsigned)lane;                                                   \
      wrec<24, 0>(word, dws, pdu, pdm, mrx);                                            \
      tbf[base + (J) - 1][lane] = word;                                                 \
    }                                                                                   \
  }
#define ITER(J)                                                                         \
  if (w == 0) W0_BLOCK(J) else W1_BLOCK(J)                                              \
  __syncthreads();

  for (int base = 0; base < 84; base += 6) {
    ITER(0) ITER(1) ITER(2) ITER(3) ITER(4) ITER(5)
  }

  // ---- epilogue: it = 84, 85 ----
  if (w == 0) {   // it=84: load bm[85] (buf1 -> bank1), ACS chunk84 (bank0)
    const float4* p = (const float4*)&bmld[1][lane][0];
#pragma unroll
    for (int j = 0; j < 6; ++j) bk1[j] = p[j];
    acsr<24, 0>(cum, dw, bk0, sgn, mrx);
    dwld[0][lane] = dw;
    dw = 0;
  } else {        // wr chunk 83
    unsigned dws = dwld[1][lane] << 8;
    unsigned word = (unsigned)lane;
    wrec<24, 0>(word, dws, pdu, pdm, mrx);
    tbf[83][lane] = word;
  }
  __syncthreads();
  if (w == 0) {   // it=85: ACS chunk85 (8 steps, bank1)
    acsr<8, 0>(cum, dw, bk1, sgn, mrx);
    dwld[1][lane] = dw;
  } else {        // wr chunk 84
    unsigned dws = dwld[0][lane] << 8;
    unsigned word = (unsigned)lane;
    wrec<24, 0>(word, dws, pdu, pdm, mrx);
    tbf[84][lane] = word;
  }
  __syncthreads();

  if (w == 0) {
    // terminal argmin over true states (tie -> smallest state)
    // final labeling = phase 2048%6 = 2: state bit j from C[(2+j)%6] = {12,8,16,32,5,6}
    const int stf = par6(lane & 12) | (par6(lane & 8) << 1) | (par6(lane & 16) << 2) |
                    (par6(lane & 32) << 3) | (par6(lane & 5) << 4) | (par6(lane & 6) << 5);
    float v = cum; int bs = stf; int bl = lane;
#pragma unroll
    for (int off = 32; off >= 1; off >>= 1) {
      const float ov = __shfl_xor(v, off, 64);
      const int os = __shfl_xor(bs, off, 64);
      const int ol = __shfl_xor(bl, off, 64);
      if (ov < v || (ov == v && os < bs)) { v = ov; bs = os; bl = ol; }
    }
    if (lane == 0) lam_sh = bl;
  } else {        // wr chunk 85 (8 steps)
    unsigned dws = dwld[1][lane] << 24;
    unsigned word = (unsigned)lane;
    wrec<8, 0>(word, dws, pdu, pdm, mrx);
    tbf[85][lane] = word;
  }
  __syncthreads();

  if (w == 1) {
    // ---- reconstruction: 86 chunk hops, prefetched rows ----
    const size_t ob = (size_t)b * T_STEPS;
    int lam = __builtin_amdgcn_readfirstlane(lam_sh);
    unsigned row = tbf[85][lane];
    for (int c = 85; c >= 0; --c) {
      unsigned nrow = 0;
      if (c > 0) nrow = tbf[c - 1][lane];
      const unsigned ww = (unsigned)__builtin_amdgcn_readlane((int)row, lam);
      const int nb = (c == 85) ? 8 : 24;
      if (lane < nb) out[ob + c * 24 + lane] = (float)((ww >> (6 + lane)) & 1u);
      lam = (int)(ww & 63u);
      row = nrow;
    }
  }
}

extern "C" void kernel_launch(void* const* d_in, const int* in_sizes, int n_in,
                              void* d_out, int out_size, void* d_ws, size_t ws_size,
                              hipStream_t stream) {
  const float* in = (const float*)d_in[0];
  float* out = (float*)d_out;
  (void)in_sizes; (void)n_in; (void)out_size; (void)d_ws; (void)ws_size;
  viterbi_kernel<<<dim3(512), dim3(128), 0, stream>>>(in, out);
}

// Round 11
// 75.944 us; speedup vs baseline: 1.1878x; 1.1878x over previous
//
#include <hip/hip_runtime.h>
#include <stdint.h>

#define T_STEPS 2048
#define NCHUNK  86            // 85 full 24-step chunks + one 8-step tail
#define LARGEF  1.0e9f
#define NB      512
typedef unsigned long long u64;
typedef unsigned uint2v __attribute__((ext_vector_type(2)));

__device__ __forceinline__ int par6(int x) { return __builtin_popcount((unsigned)x) & 1; }

// dual-basis functionals C; exchange masks m={1,2,7,15,16,32} (verified r2-r10)
constexpr int CARR[6] = {5, 6, 12, 8, 16, 32};

template<int CTRL>
__device__ __forceinline__ float xdpp(float x) {
  return __int_as_float(__builtin_amdgcn_update_dpp(0, __float_as_int(x), CTRL, 0xF, 0xF, true));
}
template<int CTRL>
__device__ __forceinline__ unsigned xdpp_u(unsigned x) {
  return (unsigned)__builtin_amdgcn_update_dpp(0, (int)x, CTRL, 0xF, 0xF, true);
}
__device__ __forceinline__ unsigned selmask_u(unsigned a_false, unsigned b_true, u64 m) {
  unsigned out;
  asm("v_cndmask_b32 %0, %1, %2, %3" : "=v"(out) : "v"(a_false), "v"(b_true), "s"(m));
  return out;
}
__device__ __forceinline__ unsigned exch16_u(unsigned x, u64 mrx) {
#if __has_builtin(__builtin_amdgcn_permlane16_swap)
  uint2v r = __builtin_amdgcn_permlane16_swap(x, x, false, false);
  return selmask_u(r.y, r.x, mrx);
#else
  (void)mrx;
  return (unsigned)__builtin_amdgcn_ds_swizzle((int)x, 0x401F);
#endif
}
__device__ __forceinline__ unsigned exch32_u(unsigned x, u64 mrx) {
#if __has_builtin(__builtin_amdgcn_permlane32_swap)
  uint2v r = __builtin_amdgcn_permlane32_swap(x, x, false, false);
  return selmask_u(r.y, r.x, mrx);
#else
  (void)mrx;
  return (unsigned)__shfl_xor((int)x, 32, 64);
#endif
}
template<int PH>
__device__ __forceinline__ float exchf(float x, const u64 (&mrx)[2]) {
  if constexpr (PH == 0) return xdpp<0xB1>(x);        // xor 1
  else if constexpr (PH == 1) return xdpp<0x4E>(x);   // xor 2
  else if constexpr (PH == 2) return xdpp<0x141>(x);  // xor 7
  else if constexpr (PH == 3) return xdpp<0x140>(x);  // xor 15
  else if constexpr (PH == 4) return __uint_as_float(exch16_u(__float_as_uint(x), mrx[0]));
  else return __uint_as_float(exch32_u(__float_as_uint(x), mrx[1]));
}
template<int PH>
__device__ __forceinline__ unsigned exchu(unsigned x, const u64 (&mrx)[2]) {
  if constexpr (PH == 0) return xdpp_u<0xB1>(x);
  else if constexpr (PH == 1) return xdpp_u<0x4E>(x);
  else if constexpr (PH == 2) return xdpp_u<0x141>(x);
  else if constexpr (PH == 3) return xdpp_u<0x140>(x);
  else if constexpr (PH == 4) return exch16_u(x, mrx[0]);
  else return exch32_u(x, mrx[1]);
}

struct Phc {
  float sae[6], sbe[6];
  unsigned sgn[6];   // pd ? 0 : 0x80000000 (sign-xor decision)
  unsigned pdu[6];   // decoded-bit constant per phase
  u64 pdm[6];        // uniform mask: lanes with odd own-pred parity
  u64 mrx[2];        // permlane swap r.x-select masks
};

__device__ __forceinline__ void mkconsts(int lane, Phc& p) {
#pragma unroll
  for (int ph = 0; ph < 6; ++ph) {
    const int pdv = par6(lane & CARR[ph]);
    int t = 0;
#pragma unroll
    for (int j = 0; j < 5; ++j) t |= par6(lane & CARR[(ph + 1 + j) % 6]) << j;
    t |= pdv << 5;
    const float sa = 1.0f - 2.0f * (float)par6(t & 45);   // poly 1011011
    const float sb = 1.0f - 2.0f * (float)par6(t & 60);   // poly 1111001
    p.sae[ph] = pdv ? -sa : sa;
    p.sbe[ph] = pdv ? -sb : sb;
    p.sgn[ph] = pdv ? 0u : 0x80000000u;
    p.pdu[ph] = (unsigned)pdv;
    p.pdm[ph] = __ballot(pdv != 0);
  }
  const u64 ODD16 = 0xFFFF0000FFFF0000ull, HI32 = 0xFFFFFFFF00000000ull;
#if __has_builtin(__builtin_amdgcn_permlane16_swap)
  {
    uint2v r = __builtin_amdgcn_permlane16_swap((unsigned)lane, (unsigned)lane, false, false);
    p.mrx[0] = (((unsigned)__builtin_amdgcn_readlane((int)r.x, 0) == 16u)) ? ~ODD16 : ODD16;
  }
#else
  p.mrx[0] = 0;
#endif
#if __has_builtin(__builtin_amdgcn_permlane32_swap)
  {
    uint2v r = __builtin_amdgcn_permlane32_swap((unsigned)lane, (unsigned)lane, false, false);
    p.mrx[1] = (((unsigned)__builtin_amdgcn_readlane((int)r.x, 0) == 32u)) ? ~HI32 : HI32;
  }
#else
  p.mrx[1] = 0;
#endif
}

// ---- hoisted branch metrics for a chunk ----
template<int N>
__device__ __forceinline__ void bmcalc(const float4 (&fy)[12], float (&bm)[24],
                                       const float (&sae)[6], const float (&sbe)[6]) {
#pragma unroll
  for (int k = 0; k < N; ++k) {
    const int ph = k % 6;
    const float y0 = (k & 1) ? fy[k >> 1].z : fy[k >> 1].x;
    const float y1 = (k & 1) ? fy[k >> 1].w : fy[k >> 1].y;
    bm[k] = fmaf(sae[ph], y0, sbe[ph] * y1);   // bit-exact vs ref
  }
}

// ---- forward core: N ACS steps; dw = 2*dw + d (d_K lands at bit N-1-K) ----
template<int N, int K>
__device__ __forceinline__ void acs(float& cum, unsigned& dw, const float (&bm)[24],
                                    const unsigned (&sgn)[6], const u64 (&mrx)[2]) {
  if constexpr (K < N) {
    constexpr int ph = K % 6;
    const float ex = exchf<ph>(cum, mrx);
    const float cA = cum + bm[K];   // own-pred candidate
    const float cB = ex - bm[K];    // partner-pred candidate
    const float D = cA - cB;        // sign exact; zero iff true tie
    cum = fminf(cA, cB);
    unsigned tmp;
    asm("v_xor_b32 %0, %2, %3\n\t"
        "v_cmp_gt_f32 vcc, 0, %0\n\t"
        "v_addc_co_u32 %1, vcc, %1, %1, vcc"
        : "=&v"(tmp), "+v"(dw)
        : "v"(D), "v"(sgn[ph]) : "vcc");
    acs<N, K + 1>(cum, dw, bm, sgn, mrx);
  }
}

// ---- chunk word reconstruction from d-bits (tp = d XOR pd; verified r10) ----
template<int N, int K>
__device__ __forceinline__ void wrec(unsigned& word, unsigned& dws, const unsigned (&pdu)[6],
                                     const u64 (&pdm)[6], const u64 (&mrx)[2]) {
  if constexpr (K < N) {
    constexpr int ph = K % 6;
    const unsigned exw = exchu<ph>(word, mrx);
    asm("v_cmp_gt_i32 vcc, 0, %1\n\t"
        "v_add_u32 %1, %1, %1\n\t"
        "s_xor_b64 vcc, vcc, %3\n\t"
        "v_cndmask_b32 %0, %0, %2, vcc"
        : "+v"(word), "+v"(dws)
        : "v"(exw), "s"(pdm[ph]) : "vcc");
    word |= pdu[ph] << (6 + K);
    wrec<N, K + 1>(word, dws, pdu, pdm, mrx);
  }
}

// ---- terminal argmin over true states (tie -> smallest state) ----
__device__ __forceinline__ int term_argmin(float cum, int lane) {
  // final labeling = phase 2048%6 = 2: state bit j from C[(2+j)%6] = {12,8,16,32,5,6}
  const int stf = par6(lane & 12) | (par6(lane & 8) << 1) | (par6(lane & 16) << 2) |
                  (par6(lane & 32) << 3) | (par6(lane & 5) << 4) | (par6(lane & 6) << 5);
  float v = cum; int bs = stf; int bl = lane;
#pragma unroll
  for (int off = 32; off >= 1; off >>= 1) {
    const float ov = __shfl_xor(v, off, 64);
    const int os = __shfl_xor(bs, off, 64);
    const int ol = __shfl_xor(bl, off, 64);
    if (ov < v || (ov == v && os < bs)) { v = ov; bs = os; bl = ol; }
  }
  return bl;
}

// ================= K1: forward pass, d-bit planes to workspace =================
__global__ __launch_bounds__(64, 1) void vit_fwd(const float* __restrict__ in,
                                                 unsigned* __restrict__ dwg,
                                                 int* __restrict__ term) {
  __shared__ float y_lds[2 * T_STEPS];   // 16 KB staged input row
  const int b = blockIdx.x;
  const int lane = threadIdx.x;
  {
    const float4* g = (const float4*)(in + (size_t)b * (2 * T_STEPS));
    float4* l = (float4*)y_lds;
#pragma unroll
    for (int i = 0; i < 16; ++i) l[i * 64 + lane] = g[i * 64 + lane];
  }
  __syncthreads();

  Phc p;
  mkconsts(lane, p);

  float cum = (lane == 0) ? 0.0f : LARGEF;
  float bm[24];
  float4 cur[12], nxt[12];
  const float4* y4 = (const float4*)y_lds;
  unsigned* dwp = dwg + (size_t)b * (NCHUNK * 64) + lane;
  unsigned dw;
#pragma unroll
  for (int j = 0; j < 12; ++j) cur[j] = y4[j];               // chunk 0
  for (int cc = 0; cc < 42; ++cc) {
    const int c0 = 2 * cc;
    bmcalc<24>(cur, bm, p.sae, p.sbe);
#pragma unroll
    for (int j = 0; j < 12; ++j) nxt[j] = y4[12 * (c0 + 1) + j];   // prefetch c0+1
    dw = 0; acs<24, 0>(cum, dw, bm, p.sgn, p.mrx);
    *dwp = dw; dwp += 64;
    bmcalc<24>(nxt, bm, p.sae, p.sbe);
#pragma unroll
    for (int j = 0; j < 12; ++j) cur[j] = y4[12 * (c0 + 2) + j];   // prefetch c0+2
    dw = 0; acs<24, 0>(cum, dw, bm, p.sgn, p.mrx);
    *dwp = dw; dwp += 64;
  }
  // chunk 84 from cur; tail (steps 2040..2047) = float4 idx 1020..1023
  bmcalc<24>(cur, bm, p.sae, p.sbe);
#pragma unroll
  for (int j = 0; j < 4; ++j) nxt[j] = y4[1020 + j];
  dw = 0; acs<24, 0>(cum, dw, bm, p.sgn, p.mrx);
  *dwp = dw; dwp += 64;
  bmcalc<8>(nxt, bm, p.sae, p.sbe);
  dw = 0; acs<8, 0>(cum, dw, bm, p.sgn, p.mrx);
  *dwp = dw;

  const int bl = term_argmin(cum, lane);
  if (lane == 0) term[b] = bl;
}

// ============ K2: massively parallel per-chunk word reconstruction ============
__global__ __launch_bounds__(256, 1) void vit_rec(const unsigned* __restrict__ dwg,
                                                  unsigned* __restrict__ tbfg) {
  const int tid = threadIdx.x;
  const int lane = tid & 63;
  const int wv = tid >> 6;
  const int idx = blockIdx.x * 4 + wv;           // (b,c) pair, 0..44031
  const unsigned ui = (unsigned)idx;
  const int c = (int)(ui % (unsigned)NCHUNK);

  Phc p;
  mkconsts(lane, p);

  const unsigned dw = dwg[(size_t)idx * 64 + lane];
  unsigned word = (unsigned)lane;
  if (c == NCHUNK - 1) {
    unsigned dws = dw << 24;
    wrec<8, 0>(word, dws, p.pdu, p.pdm, p.mrx);
  } else {
    unsigned dws = dw << 8;
    wrec<24, 0>(word, dws, p.pdu, p.pdm, p.mrx);
  }
  tbfg[(size_t)idx * 64 + lane] = word;
}

// ================= K3: 86-hop traceback, rows preloaded to VGPRs ==============
__global__ __launch_bounds__(64, 1) void vit_tb(const unsigned* __restrict__ tbfg,
                                                const int* __restrict__ term,
                                                float* __restrict__ out) {
  const int b = blockIdx.x;
  const int lane = threadIdx.x;
  unsigned rows[NCHUNK];
  const unsigned* tp = tbfg + (size_t)b * (NCHUNK * 64) + lane;
#pragma unroll
  for (int c = 0; c < NCHUNK; ++c) rows[c] = tp[c * 64];   // all loads in flight
  int lam = term[b];
  const size_t ob = (size_t)b * T_STEPS;
#pragma unroll
  for (int cc = 0; cc < NCHUNK; ++cc) {
    const int c = NCHUNK - 1 - cc;
    const unsigned w = (unsigned)__builtin_amdgcn_readlane((int)rows[c], lam);
    const int nb = (c == NCHUNK - 1) ? 8 : 24;
    if (lane < nb) out[ob + c * 24 + lane] = (float)((w >> (6 + lane)) & 1u);
    lam = (int)(w & 63u);
  }
}

// ====== fallback: single-kernel (fwd + in-wave wrec + traceback), no ws =======
__global__ __launch_bounds__(64, 1) void vit_fb(const float* __restrict__ in,
                                                float* __restrict__ out) {
  __shared__ float y_lds[2 * T_STEPS];     // 16 KB
  __shared__ unsigned dwl[NCHUNK][64];     // 21.5 KB d-bit planes
  __shared__ unsigned tbf[NCHUNK][64];     // 21.5 KB path/anc words
  const int b = blockIdx.x;
  const int lane = threadIdx.x;
  {
    const float4* g = (const float4*)(in + (size_t)b * (2 * T_STEPS));
    float4* l = (float4*)y_lds;
#pragma unroll
    for (int i = 0; i < 16; ++i) l[i * 64 + lane] = g[i * 64 + lane];
  }
  __syncthreads();
  Phc p;
  mkconsts(lane, p);
  float cum = (lane == 0) ? 0.0f : LARGEF;
  float bm[24];
  float4 cur[12], nxt[12];
  const float4* y4 = (const float4*)y_lds;
  unsigned dw;
#pragma unroll
  for (int j = 0; j < 12; ++j) cur[j] = y4[j];
  for (int cc = 0; cc < 42; ++cc) {
    const int c0 = 2 * cc;
    bmcalc<24>(cur, bm, p.sae, p.sbe);
#pragma unroll
    for (int j = 0; j < 12; ++j) nxt[j] = y4[12 * (c0 + 1) + j];
    dw = 0; acs<24, 0>(cum, dw, bm, p.sgn, p.mrx);
    dwl[c0][lane] = dw;
    bmcalc<24>(nxt, bm, p.sae, p.sbe);
#pragma unroll
    for (int j = 0; j < 12; ++j) cur[j] = y4[12 * (c0 + 2) + j];
    dw = 0; acs<24, 0>(cum, dw, bm, p.sgn, p.mrx);
    dwl[c0 + 1][lane] = dw;
  }
  bmcalc<24>(cur, bm, p.sae, p.sbe);
#pragma unroll
  for (int j = 0; j < 4; ++j) nxt[j] = y4[1020 + j];
  dw = 0; acs<24, 0>(cum, dw, bm, p.sgn, p.mrx);
  dwl[84][lane] = dw;
  bmcalc<8>(nxt, bm, p.sae, p.sbe);
  dw = 0; acs<8, 0>(cum, dw, bm, p.sgn, p.mrx);
  dwl[85][lane] = dw;

  for (int c = 0; c < 85; ++c) {
    unsigned dws = dwl[c][lane] << 8;
    unsigned word = (unsigned)lane;
    wrec<24, 0>(word, dws, p.pdu, p.pdm, p.mrx);
    tbf[c][lane] = word;
  }
  {
    unsigned dws = dwl[85][lane] << 24;
    unsigned word = (unsigned)lane;
    wrec<8, 0>(word, dws, p.pdu, p.pdm, p.mrx);
    tbf[85][lane] = word;
  }

  int lam = __builtin_amdgcn_readfirstlane(term_argmin(cum, lane));
  const size_t ob = (size_t)b * T_STEPS;
  unsigned row = tbf[85][lane];
  for (int c = 85; c >= 0; --c) {
    unsigned nrow = 0;
    if (c > 0) nrow = tbf[c - 1][lane];
    const unsigned w = (unsigned)__builtin_amdgcn_readlane((int)row, lam);
    const int nb = (c == 85) ? 8 : 24;
    if (lane < nb) out[ob + c * 24 + lane] = (float)((w >> (6 + lane)) & 1u);
    lam = (int)(w & 63u);
    row = nrow;
  }
}

extern "C" void kernel_launch(void* const* d_in, const int* in_sizes, int n_in,
                              void* d_out, int out_size, void* d_ws, size_t ws_size,
                              hipStream_t stream) {
  const float* in = (const float*)d_in[0];
  float* out = (float*)d_out;
  (void)in_sizes; (void)n_in; (void)out_size;
  const size_t nwords = (size_t)NB * NCHUNK * 64;            // 2,818,048
  const size_t need = nwords * 4 * 2 + NB * 4;               // dwg + tbfg + term
  if (ws_size >= need) {
    unsigned* dwg = (unsigned*)d_ws;
    unsigned* tbfg = dwg + nwords;
    int* term = (int*)(tbfg + nwords);
    vit_fwd<<<dim3(NB), dim3(64), 0, stream>>>(in, dwg, term);
    vit_rec<<<dim3((NB * NCHUNK) / 4), dim3(256), 0, stream>>>(dwg, tbfg);
    vit_tb<<<dim3(NB), dim3(64), 0, stream>>>(tbfg, term, out);
  } else {
    vit_fb<<<dim3(NB), dim3(64), 0, stream>>>(in, out);
  }
}